// Round 1
// baseline (242.085 us; speedup 1.0000x reference)
//
#include <hip/hip_runtime.h>
#include <hip/hip_bf16.h>
#include <stdint.h>

// Problem constants
#define NB 2
#define NS 2048
#define NE 1024
#define NH 16
#define ND 64

typedef __attribute__((ext_vector_type(4))) float f32x4;
typedef __attribute__((ext_vector_type(8))) short s16x8;
typedef __attribute__((ext_vector_type(4))) unsigned short u16x4;

__device__ __forceinline__ unsigned short f2bf(float f) {
  union { float f; unsigned int i; } u; u.f = f;
  unsigned int r = u.i + 0x7FFFu + ((u.i >> 16) & 1u);  // RNE
  return (unsigned short)(r >> 16);
}

__device__ __forceinline__ void gload_lds16(const void* g, void* l) {
  __builtin_amdgcn_global_load_lds(
      (const __attribute__((address_space(1))) uint32_t*)g,
      (__attribute__((address_space(3))) uint32_t*)l, 16, 0, 0);
}

__device__ __forceinline__ f32x4 mfma16(s16x8 a, s16x8 b, f32x4 c) {
  return __builtin_amdgcn_mfma_f32_16x16x32_bf16(a, b, c, 0, 0, 0);
}

// ---------------- f32 -> bf16 convert ----------------
__global__ void conv_bf16(const float* __restrict__ src,
                          unsigned short* __restrict__ dst, int n4) {
  int i = blockIdx.x * blockDim.x + threadIdx.x;
  int stride = gridDim.x * blockDim.x;
  for (; i < n4; i += stride) {
    float4 v = ((const float4*)src)[i];
    u16x4 o;
    o.x = f2bf(v.x); o.y = f2bf(v.y); o.z = f2bf(v.z); o.w = f2bf(v.w);
    ((u16x4*)dst)[i] = o;
  }
}

// ---------------- GEMM: C[M,N] = A[M,K] * W[N,K]^T + bias ----------------
// EPI 0: bf16 out row-major [M,N]
// EPI 1: bf16 out transposed per-head: out[(b*NE + n)*NS + s]  (for V^T)
// EPI 2: f32 out row-major [M,N]
template <int EPI>
__global__ __launch_bounds__(256, 2) void gemm_bt(
    const unsigned short* __restrict__ A, const unsigned short* __restrict__ W,
    const float* __restrict__ bias, void* __restrict__ out,
    int M, int N, int K) {
  __shared__ char smem[32768];
  char* As = smem;
  char* Bs = smem + 16384;
  const int t = threadIdx.x;
  const int lane = t & 63;
  const int wv = t >> 6;
  const int wr = wv >> 1, wc = wv & 1;  // 2x2 wave grid, 64x64 each
  const int bm = blockIdx.y * 128, bn = blockIdx.x * 128;
  const int lr = lane & 15, lg = lane >> 4;

  f32x4 acc[4][4] = {};

  for (int k0 = 0; k0 < K; k0 += 64) {
    __syncthreads();
    // stage A tile [128][64] bf16 (16KB): XOR-swizzled source, linear LDS
#pragma unroll
    for (int r = 0; r < 4; ++r) {
      int lin = r * 256 + t;
      int row = lin >> 3;
      int cb = (lin & 7) << 4;
      int scb = cb ^ ((row & 7) << 4);
      gload_lds16((const char*)(A + (size_t)(bm + row) * K + k0) + scb,
                  As + (size_t)(r * 256 + (t & ~63)) * 16);
    }
#pragma unroll
    for (int r = 0; r < 4; ++r) {
      int lin = r * 256 + t;
      int row = lin >> 3;
      int cb = (lin & 7) << 4;
      int scb = cb ^ ((row & 7) << 4);
      gload_lds16((const char*)(W + (size_t)(bn + row) * K + k0) + scb,
                  Bs + (size_t)(r * 256 + (t & ~63)) * 16);
    }
    asm volatile("s_waitcnt vmcnt(0)" ::: "memory");
    __syncthreads();

    s16x8 af[4][2], bfr[4][2];
#pragma unroll
    for (int mf = 0; mf < 4; ++mf)
#pragma unroll
      for (int kk = 0; kk < 2; ++kk) {
        int row = wr * 64 + mf * 16 + lr;
        int cb = (lg << 4) + (kk << 6);
        af[mf][kk] = *(const s16x8*)(As + row * 128 + (cb ^ ((row & 7) << 4)));
      }
#pragma unroll
    for (int nf = 0; nf < 4; ++nf)
#pragma unroll
      for (int kk = 0; kk < 2; ++kk) {
        int row = wc * 64 + nf * 16 + lr;
        int cb = (lg << 4) + (kk << 6);
        bfr[nf][kk] = *(const s16x8*)(Bs + row * 128 + (cb ^ ((row & 7) << 4)));
      }
#pragma unroll
    for (int mf = 0; mf < 4; ++mf)
#pragma unroll
      for (int nf = 0; nf < 4; ++nf)
#pragma unroll
        for (int kk = 0; kk < 2; ++kk)
          acc[mf][nf] = mfma16(af[mf][kk], bfr[nf][kk], acc[mf][nf]);
  }

  // epilogue: C/D layout col = lane&15, row = (lane>>4)*4 + reg
#pragma unroll
  for (int mf = 0; mf < 4; ++mf)
#pragma unroll
    for (int nf = 0; nf < 4; ++nf) {
      int m0 = bm + wr * 64 + mf * 16 + (lg << 2);
      int n = bn + wc * 64 + nf * 16 + lr;
      float bv = bias[n];
      if constexpr (EPI == 0) {
        unsigned short* C = (unsigned short*)out;
#pragma unroll
        for (int r = 0; r < 4; ++r)
          C[(size_t)(m0 + r) * N + n] = f2bf(acc[mf][nf][r] + bv);
      } else if constexpr (EPI == 1) {
        unsigned short* C = (unsigned short*)out;
        int b = m0 >> 11, s = m0 & 2047;  // S=2048
        u16x4 o;
        o.x = f2bf(acc[mf][nf][0] + bv);
        o.y = f2bf(acc[mf][nf][1] + bv);
        o.z = f2bf(acc[mf][nf][2] + bv);
        o.w = f2bf(acc[mf][nf][3] + bv);
        *(u16x4*)&C[((size_t)b * NE + n) * NS + s] = o;
      } else {
        float* C = (float*)out;
#pragma unroll
        for (int r = 0; r < 4; ++r)
          C[(size_t)(m0 + r) * N + n] = acc[mf][nf][r] + bv;
      }
    }
}

// ---------------- Flash attention ----------------
// grid (S/128, B*H), 256 threads = 4 waves; each wave owns 32 q-rows.
#define PSTR 72  // padded P stride (elements); 144B rows stay 16B-aligned

__global__ __launch_bounds__(256, 2) void attn_fwd(
    const unsigned short* __restrict__ qb, const unsigned short* __restrict__ kb,
    const unsigned short* __restrict__ vt, const int* __restrict__ mask,
    unsigned short* __restrict__ ob) {
  __shared__ char smem[8192 + 8192 + 128 * PSTR * 2];
  char* Ks = smem;
  char* Vs = smem + 8192;
  char* Ps = smem + 16384;
  const int t = threadIdx.x, lane = t & 63, wv = t >> 6;
  const int lr = lane & 15, lg = lane >> 4;
  const int bh = blockIdx.y, b = bh >> 4, h = bh & 15;
  const int q0 = blockIdx.x * 128;
  const float scale = 0.125f;  // 1/sqrt(64)

  // Q fragments in registers (A-operand: row=q, k=d)
  s16x8 qf[2][2];
#pragma unroll
  for (int mf = 0; mf < 2; ++mf)
#pragma unroll
    for (int kk = 0; kk < 2; ++kk) {
      int qr = q0 + wv * 32 + mf * 16 + lr;
      int d = (lg << 3) + (kk << 5);
      qf[mf][kk] = *(const s16x8*)&qb[((size_t)(b * NS + qr)) * NE + h * ND + d];
    }

  f32x4 oacc[2][4] = {};
  float mrow[2][4], lrow[2][4];
#pragma unroll
  for (int mf = 0; mf < 2; ++mf)
#pragma unroll
    for (int r = 0; r < 4; ++r) { mrow[mf][r] = -3.0e38f; lrow[mf][r] = 0.f; }

  for (int kt = 0; kt < NS; kt += 64) {
    __syncthreads();
    // stage K tile [64 keys][64 d] (8KB)
#pragma unroll
    for (int r = 0; r < 2; ++r) {
      int lin = r * 256 + t;
      int row = lin >> 3;
      int cb = (lin & 7) << 4;
      int scb = cb ^ ((row & 7) << 4);
      gload_lds16((const char*)&kb[((size_t)(b * NS + kt + row)) * NE + h * ND] + scb,
                  Ks + (r * 256 + (t & ~63)) * 16);
    }
    // stage V^T tile [64 d][64 keys] (8KB) from head-transposed vt
#pragma unroll
    for (int r = 0; r < 2; ++r) {
      int lin = r * 256 + t;
      int row = lin >> 3;
      int cb = (lin & 7) << 4;
      int scb = cb ^ ((row & 7) << 4);
      gload_lds16((const char*)&vt[((size_t)((b * NH + h) * ND + row)) * NS + kt] + scb,
                  Vs + (r * 256 + (t & ~63)) * 16);
    }
    asm volatile("s_waitcnt vmcnt(0)" ::: "memory");
    __syncthreads();

    // QK^T: B-operand = K rows (col=key, k=d)
    s16x8 kf[4][2];
#pragma unroll
    for (int nf = 0; nf < 4; ++nf)
#pragma unroll
      for (int kk = 0; kk < 2; ++kk) {
        int row = nf * 16 + lr;
        int cb = (lg << 4) + (kk << 6);
        kf[nf][kk] = *(const s16x8*)(Ks + row * 128 + (cb ^ ((row & 7) << 4)));
      }
    f32x4 sacc[2][4] = {};
#pragma unroll
    for (int mf = 0; mf < 2; ++mf)
#pragma unroll
      for (int nf = 0; nf < 4; ++nf)
#pragma unroll
        for (int kk = 0; kk < 2; ++kk)
          sacc[mf][nf] = mfma16(qf[mf][kk], kf[nf][kk], sacc[mf][nf]);

    // scale + mask (mask indexes keys)
    int mcol[4];
#pragma unroll
    for (int nf = 0; nf < 4; ++nf) mcol[nf] = mask[b * NS + kt + nf * 16 + lr];
#pragma unroll
    for (int mf = 0; mf < 2; ++mf)
#pragma unroll
      for (int nf = 0; nf < 4; ++nf)
#pragma unroll
        for (int r = 0; r < 4; ++r) {
          float s = sacc[mf][nf][r] * scale;
          sacc[mf][nf][r] = (mcol[nf] == 0) ? -1.0e30f : s;
        }

    // online softmax; rows live in 16-lane groups (row=(lg<<2)+r per frag)
#pragma unroll
    for (int mf = 0; mf < 2; ++mf)
#pragma unroll
      for (int r = 0; r < 4; ++r) {
        float mx = fmaxf(fmaxf(sacc[mf][0][r], sacc[mf][1][r]),
                         fmaxf(sacc[mf][2][r], sacc[mf][3][r]));
        mx = fmaxf(mx, __shfl_xor(mx, 1));
        mx = fmaxf(mx, __shfl_xor(mx, 2));
        mx = fmaxf(mx, __shfl_xor(mx, 4));
        mx = fmaxf(mx, __shfl_xor(mx, 8));
        float mnew = fmaxf(mrow[mf][r], mx);
        float corr = __expf(mrow[mf][r] - mnew);
        mrow[mf][r] = mnew;
        float rs = 0.f;
        int qrl = wv * 32 + mf * 16 + (lg << 2) + r;
#pragma unroll
        for (int nf = 0; nf < 4; ++nf) {
          float p = __expf(sacc[mf][nf][r] - mnew);
          rs += p;
          *(unsigned short*)(Ps + ((size_t)qrl * PSTR + nf * 16 + lr) * 2) = f2bf(p);
        }
        rs += __shfl_xor(rs, 1);
        rs += __shfl_xor(rs, 2);
        rs += __shfl_xor(rs, 4);
        rs += __shfl_xor(rs, 8);
        lrow[mf][r] = lrow[mf][r] * corr + rs;
#pragma unroll
        for (int nf = 0; nf < 4; ++nf) oacc[mf][nf][r] *= corr;
      }

    __syncthreads();  // P writes -> P reads (cross-lane within wave)

    // PV: A = P (row=q, k=key) from LDS; B = V^T rows (col=d, k=key)
    s16x8 pf[2][2], vf[4][2];
#pragma unroll
    for (int mf = 0; mf < 2; ++mf)
#pragma unroll
      for (int kk = 0; kk < 2; ++kk) {
        int qrl = wv * 32 + mf * 16 + lr;
        int keb = (lg << 4) + (kk << 6);
        pf[mf][kk] = *(const s16x8*)(Ps + qrl * (PSTR * 2) + keb);
      }
#pragma unroll
    for (int nf = 0; nf < 4; ++nf)
#pragma unroll
      for (int kk = 0; kk < 2; ++kk) {
        int row = nf * 16 + lr;
        int cb = (lg << 4) + (kk << 6);
        vf[nf][kk] = *(const s16x8*)(Vs + row * 128 + (cb ^ ((row & 7) << 4)));
      }
#pragma unroll
    for (int mf = 0; mf < 2; ++mf)
#pragma unroll
      for (int nf = 0; nf < 4; ++nf)
#pragma unroll
        for (int kk = 0; kk < 2; ++kk)
          oacc[mf][nf] = mfma16(pf[mf][kk], vf[nf][kk], oacc[mf][nf]);
  }

  // normalize + write
#pragma unroll
  for (int mf = 0; mf < 2; ++mf)
#pragma unroll
    for (int nf = 0; nf < 4; ++nf)
#pragma unroll
      for (int r = 0; r < 4; ++r) {
        int q = q0 + wv * 32 + mf * 16 + (lg << 2) + r;
        int d = nf * 16 + lr;
        ob[((size_t)(b * NS + q)) * NE + h * ND + d] =
            f2bf(oacc[mf][nf][r] / lrow[mf][r]);
      }
}

// ---------------- launch ----------------
extern "C" void kernel_launch(void* const* d_in, const int* in_sizes, int n_in,
                              void* d_out, int out_size, void* d_ws, size_t ws_size,
                              hipStream_t stream) {
  const float* queries = (const float*)d_in[0];
  const float* keys = (const float*)d_in[1];
  // d_in[2] (values) is unused by the reference
  const int* mask = (const int*)d_in[3];
  const float* bq = (const float*)d_in[5];
  const float* bk = (const float*)d_in[7];
  const float* bv = (const float*)d_in[9];
  const float* bo = (const float*)d_in[11];
  const float* Wq = (const float*)d_in[4];
  const float* Wk = (const float*)d_in[6];
  const float* Wv = (const float*)d_in[8];
  const float* Wo = (const float*)d_in[10];
  float* out = (float*)d_out;

  char* ws = (char*)d_ws;
  const size_t SZ_X = (size_t)NB * NS * NE * 2;  // 8 MiB
  const size_t SZ_W = (size_t)NE * NE * 2;       // 2 MiB
  unsigned short* qbf = (unsigned short*)(ws);
  unsigned short* kbf = (unsigned short*)(ws + SZ_X);
  unsigned short* wqb = (unsigned short*)(ws + 2 * SZ_X);
  unsigned short* wkb = (unsigned short*)(ws + 2 * SZ_X + SZ_W);
  unsigned short* wvb = (unsigned short*)(ws + 2 * SZ_X + 2 * SZ_W);
  unsigned short* wob = (unsigned short*)(ws + 2 * SZ_X + 3 * SZ_W);
  unsigned short* qp  = (unsigned short*)(ws + 2 * SZ_X + 4 * SZ_W);
  unsigned short* kp  = (unsigned short*)(ws + 3 * SZ_X + 4 * SZ_W);
  unsigned short* vtp = (unsigned short*)(ws + 4 * SZ_X + 4 * SZ_W);
  unsigned short* ao  = (unsigned short*)(ws + 5 * SZ_X + 4 * SZ_W);

  int nX4 = NB * NS * NE / 4, nW4 = NE * NE / 4;
  conv_bf16<<<2048, 256, 0, stream>>>(queries, qbf, nX4);
  conv_bf16<<<2048, 256, 0, stream>>>(keys, kbf, nX4);
  conv_bf16<<<1024, 256, 0, stream>>>(Wq, wqb, nW4);
  conv_bf16<<<1024, 256, 0, stream>>>(Wk, wkb, nW4);
  conv_bf16<<<1024, 256, 0, stream>>>(Wv, wvb, nW4);
  conv_bf16<<<1024, 256, 0, stream>>>(Wo, wob, nW4);

  dim3 gg(NE / 128, (NB * NS) / 128);  // (8, 32)
  gemm_bt<0><<<gg, 256, 0, stream>>>(qbf, wqb, bq, qp, NB * NS, NE, NE);
  gemm_bt<0><<<gg, 256, 0, stream>>>(kbf, wkb, bk, kp, NB * NS, NE, NE);
  gemm_bt<1><<<gg, 256, 0, stream>>>(kbf, wvb, bv, vtp, NB * NS, NE, NE);

  dim3 ga(NS / 128, NB * NH);  // (16, 32)
  attn_fwd<<<ga, 256, 0, stream>>>(qp, kp, vtp, mask, ao);

  gemm_bt<2><<<gg, 256, 0, stream>>>(ao, wob, bo, out, NB * NS, NE, NE);
}

// Round 2
// 144.372 us; speedup vs baseline: 1.6768x; 1.6768x over previous
//
#include <hip/hip_runtime.h>
#include <hip/hip_bf16.h>
#include <stdint.h>

// Problem constants
#define NB 2
#define NS 2048
#define NE 1024
#define NH 16
#define ND 64

typedef __attribute__((ext_vector_type(4))) float f32x4;
typedef __attribute__((ext_vector_type(16))) float f32x16;
typedef __attribute__((ext_vector_type(8))) short s16x8;
typedef __attribute__((ext_vector_type(4))) unsigned short u16x4;

__device__ __forceinline__ unsigned short f2bf(float f) {
  union { float f; unsigned int i; } u; u.f = f;
  unsigned int r = u.i + 0x7FFFu + ((u.i >> 16) & 1u);  // RNE
  return (unsigned short)(r >> 16);
}

__device__ __forceinline__ unsigned cvtpk_bf16(float lo, float hi) {
  unsigned r;
  asm("v_cvt_pk_bf16_f32 %0, %1, %2" : "=v"(r) : "v"(lo), "v"(hi));
  return r;
}

__device__ __forceinline__ void gload_lds16(const void* g, void* l) {
  __builtin_amdgcn_global_load_lds(
      (const __attribute__((address_space(1))) uint32_t*)g,
      (__attribute__((address_space(3))) uint32_t*)l, 16, 0, 0);
}

__device__ __forceinline__ f32x4 mfma16(s16x8 a, s16x8 b, f32x4 c) {
  return __builtin_amdgcn_mfma_f32_16x16x32_bf16(a, b, c, 0, 0, 0);
}
__device__ __forceinline__ f32x16 mfma32(s16x8 a, s16x8 b, f32x16 c) {
  return __builtin_amdgcn_mfma_f32_32x32x16_bf16(a, b, c, 0, 0, 0);
}

// ---------------- f32 -> bf16 converts (fused) ----------------
__global__ void conv_x2(const float* __restrict__ a, const float* __restrict__ b,
                        unsigned short* __restrict__ da, unsigned short* __restrict__ db,
                        int n4) {
  const float* s = blockIdx.y ? b : a;
  unsigned short* d = blockIdx.y ? db : da;
  int i = blockIdx.x * blockDim.x + threadIdx.x;
  int stride = gridDim.x * blockDim.x;
  for (; i < n4; i += stride) {
    float4 v = ((const float4*)s)[i];
    u16x4 o;
    o.x = f2bf(v.x); o.y = f2bf(v.y); o.z = f2bf(v.z); o.w = f2bf(v.w);
    ((u16x4*)d)[i] = o;
  }
}

__global__ void conv_w4(const float* __restrict__ s0, const float* __restrict__ s1,
                        const float* __restrict__ s2, const float* __restrict__ s3,
                        unsigned short* __restrict__ d0, unsigned short* __restrict__ d1,
                        unsigned short* __restrict__ d2, unsigned short* __restrict__ d3,
                        int n4) {
  const float* s; unsigned short* d;
  switch (blockIdx.y) {
    case 0: s = s0; d = d0; break;
    case 1: s = s1; d = d1; break;
    case 2: s = s2; d = d2; break;
    default: s = s3; d = d3; break;
  }
  int i = blockIdx.x * blockDim.x + threadIdx.x;
  int stride = gridDim.x * blockDim.x;
  for (; i < n4; i += stride) {
    float4 v = ((const float4*)s)[i];
    u16x4 o;
    o.x = f2bf(v.x); o.y = f2bf(v.y); o.z = f2bf(v.z); o.w = f2bf(v.w);
    ((u16x4*)d)[i] = o;
  }
}

// ---------------- GEMM: C[M,N] = A[M,K] * W[N,K]^T + bias ----------------
// EPI 0: bf16 out row-major [M,N]
// EPI 1: bf16 out transposed per-head: out[(b*NE + n)*NS + s]  (for V^T)
// EPI 2: f32 out row-major [M,N]
template <int EPI, int BM>
__global__ __launch_bounds__(256, 2) void gemm_bt(
    const unsigned short* __restrict__ A, const unsigned short* __restrict__ W,
    const float* __restrict__ bias, void* __restrict__ out,
    int M, int N, int K) {
  constexpr int WM = BM / 2;   // wave tile rows (2x2 wave grid)
  constexpr int MF = WM / 16;  // m fragments per wave
  __shared__ char smem[BM * 128 + 16384];
  char* As = smem;
  char* Bs = smem + BM * 128;
  const int t = threadIdx.x;
  const int lane = t & 63;
  const int wv = t >> 6;
  const int wr = wv >> 1, wc = wv & 1;
  const int bm = blockIdx.y * BM, bn = blockIdx.x * 128;
  const int lr = lane & 15, lg = lane >> 4;

  f32x4 acc[MF][4] = {};

  for (int k0 = 0; k0 < K; k0 += 64) {
    __syncthreads();
#pragma unroll
    for (int r = 0; r < BM / 32; ++r) {
      int lin = r * 256 + t;
      int row = lin >> 3;
      int scb = ((lin & 7) << 4) ^ ((row & 7) << 4);
      gload_lds16((const char*)(A + (size_t)(bm + row) * K + k0) + scb,
                  As + (size_t)(r * 256 + (t & ~63)) * 16);
    }
#pragma unroll
    for (int r = 0; r < 4; ++r) {
      int lin = r * 256 + t;
      int row = lin >> 3;
      int scb = ((lin & 7) << 4) ^ ((row & 7) << 4);
      gload_lds16((const char*)(W + (size_t)(bn + row) * K + k0) + scb,
                  Bs + (size_t)(r * 256 + (t & ~63)) * 16);
    }
    asm volatile("s_waitcnt vmcnt(0)" ::: "memory");
    __syncthreads();

    s16x8 af[MF][2], bfr[4][2];
#pragma unroll
    for (int mf = 0; mf < MF; ++mf)
#pragma unroll
      for (int kk = 0; kk < 2; ++kk) {
        int row = wr * WM + mf * 16 + lr;
        int cb = (lg << 4) + (kk << 6);
        af[mf][kk] = *(const s16x8*)(As + row * 128 + (cb ^ ((row & 7) << 4)));
      }
#pragma unroll
    for (int nf = 0; nf < 4; ++nf)
#pragma unroll
      for (int kk = 0; kk < 2; ++kk) {
        int row = wc * 64 + nf * 16 + lr;
        int cb = (lg << 4) + (kk << 6);
        bfr[nf][kk] = *(const s16x8*)(Bs + row * 128 + (cb ^ ((row & 7) << 4)));
      }
#pragma unroll
    for (int mf = 0; mf < MF; ++mf)
#pragma unroll
      for (int nf = 0; nf < 4; ++nf)
#pragma unroll
        for (int kk = 0; kk < 2; ++kk)
          acc[mf][nf] = mfma16(af[mf][kk], bfr[nf][kk], acc[mf][nf]);
  }

  // epilogue: C/D layout col = lane&15, row = (lane>>4)*4 + reg
#pragma unroll
  for (int mf = 0; mf < MF; ++mf)
#pragma unroll
    for (int nf = 0; nf < 4; ++nf) {
      int m0 = bm + wr * WM + mf * 16 + (lg << 2);
      int n = bn + wc * 64 + nf * 16 + lr;
      float bv = bias[n];
      if constexpr (EPI == 0) {
        unsigned short* C = (unsigned short*)out;
#pragma unroll
        for (int r = 0; r < 4; ++r)
          C[(size_t)(m0 + r) * N + n] = f2bf(acc[mf][nf][r] + bv);
      } else if constexpr (EPI == 1) {
        unsigned short* C = (unsigned short*)out;
        int b = m0 >> 11, s = m0 & 2047;  // S=2048
        u16x4 o;
        o.x = f2bf(acc[mf][nf][0] + bv);
        o.y = f2bf(acc[mf][nf][1] + bv);
        o.z = f2bf(acc[mf][nf][2] + bv);
        o.w = f2bf(acc[mf][nf][3] + bv);
        *(u16x4*)&C[((size_t)b * NE + n) * NS + s] = o;
      } else {
        float* C = (float*)out;
#pragma unroll
        for (int r = 0; r < 4; ++r)
          C[(size_t)(m0 + r) * N + n] = acc[mf][nf][r] + bv;
      }
    }
}

// ---------------- Flash attention (swapped-operand 32x32 structure) ----------------
// grid (S/128, B*H), 256 threads = 4 waves; each wave owns 32 q-rows.
// ST = mfma(A=K, B=Q) -> lane q = lane&31, keys crow(r,hi)+32t (in-register softmax)
// O^T = mfma(A=V^T, B=P^T) -> lane q = lane&31, d = crow(r,hi)+32td
__global__ __launch_bounds__(256, 2) void attn_fwd(
    const unsigned short* __restrict__ qb, const unsigned short* __restrict__ kb,
    const unsigned short* __restrict__ vt, const int* __restrict__ mask,
    unsigned short* __restrict__ ob) {
  __shared__ char smem[32768];  // 2 x (K 8KB + V 8KB)
  const int t = threadIdx.x, lane = t & 63, wv = t >> 6;
  const int l31 = lane & 31, hi = lane >> 5;
  const int bh = blockIdx.y, b = bh >> 4, h = bh & 15;
  const int q = blockIdx.x * 128 + wv * 32 + l31;
  const float C = 0.18033688f;  // (1/sqrt(64)) * log2(e)

  // Q fragments (B-operand: col=q=lane&31, k = 16*ks + 8*hi + e)
  s16x8 qf[4];
#pragma unroll
  for (int ks = 0; ks < 4; ++ks)
    qf[ks] = *(const s16x8*)&qb[((size_t)(b * NS + q)) * NE + h * ND + ks * 16 + hi * 8];

  f32x16 oacc[2] = {};
  float m = -1e30f, l = 0.f;

  auto stage = [&](int buf, int kt) {
    char* Ks = smem + buf * 16384;
    char* Vs = Ks + 8192;
#pragma unroll
    for (int r = 0; r < 2; ++r) {
      int lin = r * 256 + t;
      int row = lin >> 3;
      int scb = ((lin & 7) << 4) ^ ((row & 7) << 4);
      gload_lds16((const char*)&kb[((size_t)(b * NS + kt + row)) * NE + h * ND] + scb,
                  Ks + (r * 256 + (t & ~63)) * 16);
    }
#pragma unroll
    for (int r = 0; r < 2; ++r) {
      int lin = r * 256 + t;
      int row = lin >> 3;
      int scb = ((lin & 7) << 4) ^ ((row & 7) << 4);
      gload_lds16((const char*)&vt[((size_t)((b * NH + h) * ND + row)) * NS + kt] + scb,
                  Vs + (r * 256 + (t & ~63)) * 16);
    }
  };

  stage(0, 0);
  asm volatile("s_waitcnt vmcnt(0)" ::: "memory");
  __syncthreads();

  for (int kt = 0; kt < NS; kt += 64) {
    const int cur = (kt >> 6) & 1;
    if (kt + 64 < NS) stage(cur ^ 1, kt + 64);
    const char* Ks = smem + cur * 16384;
    const char* Vs = Ks + 8192;

    int mk = mask[b * NS + kt + lane];

    // QK^T (swapped): ST[key][q]
    f32x16 st[2] = {};
#pragma unroll
    for (int t2 = 0; t2 < 2; ++t2)
#pragma unroll
      for (int ks = 0; ks < 4; ++ks) {
        int row = t2 * 32 + l31;
        s16x8 kf = *(const s16x8*)(Ks + row * 128 + ((ks * 32 + hi * 16) ^ ((row & 7) << 4)));
        st[t2] = mfma32(kf, qf[ks], st[t2]);
      }

    // tile max (lane-local tree + one cross-half exchange)
    float tm[16];
#pragma unroll
    for (int r = 0; r < 16; ++r) tm[r] = fmaxf(st[0][r], st[1][r]);
#pragma unroll
    for (int s = 8; s > 0; s >>= 1)
#pragma unroll
      for (int r = 0; r < s; ++r) tm[r] = fmaxf(tm[r], tm[r + s]);
    float mx = fmaxf(tm[0], __shfl_xor(tm[0], 32));

    // defer-max (T13): skip O rescale when growth small
    if (!__all(mx - m <= 44.0f)) {
      float mnew = fmaxf(m, mx);
      float corr = __builtin_amdgcn_exp2f((m - mnew) * C);
#pragma unroll
      for (int td = 0; td < 2; ++td)
#pragma unroll
        for (int r = 0; r < 16; ++r) oacc[td][r] *= corr;
      l *= corr;
      m = mnew;
    }
    const float mC = m * C;

    float p[32];
#pragma unroll
    for (int t2 = 0; t2 < 2; ++t2)
#pragma unroll
      for (int r = 0; r < 16; ++r)
        p[t2 * 16 + r] = __builtin_amdgcn_exp2f(__builtin_fmaf(st[t2][r], C, -mC));

    // mask: softmax is invariant to over-large m, so zeroing p suffices
    unsigned long long bal = __ballot(mk != 0);
    if (bal != ~0ull) {
#pragma unroll
      for (int t2 = 0; t2 < 2; ++t2)
#pragma unroll
        for (int r = 0; r < 16; ++r) {
          int key = t2 * 32 + (r & 3) + 8 * (r >> 2) + 4 * hi;
          if (!((bal >> key) & 1)) p[t2 * 16 + r] = 0.f;
        }
    }

    // row sum
    float ps[16];
#pragma unroll
    for (int r = 0; r < 16; ++r) ps[r] = p[r] + p[16 + r];
#pragma unroll
    for (int s = 8; s > 0; s >>= 1)
#pragma unroll
      for (int r = 0; r < s; ++r) ps[r] += ps[r + s];
    l += ps[0] + __shfl_xor(ps[0], 32);

    // pack P into PV B-fragments (T12: cvt_pk + lane^32 exchange)
    s16x8 pf[4];
#pragma unroll
    for (int ks = 0; ks < 4; ++ks) {
      unsigned wreg[4];
#pragma unroll
      for (int w = 0; w < 2; ++w) {
        unsigned x = cvtpk_bf16(p[8 * ks + 2 * w], p[8 * ks + 2 * w + 1]);
        unsigned y = cvtpk_bf16(p[8 * ks + 4 + 2 * w], p[8 * ks + 4 + 2 * w + 1]);
        unsigned xs = (unsigned)__shfl_xor((int)x, 32);
        unsigned ys = (unsigned)__shfl_xor((int)y, 32);
        wreg[w] = hi ? ys : x;
        wreg[w + 2] = hi ? y : xs;
      }
      union { unsigned u[4]; s16x8 v; } pu;
      pu.u[0] = wreg[0]; pu.u[1] = wreg[1]; pu.u[2] = wreg[2]; pu.u[3] = wreg[3];
      pf[ks] = pu.v;
    }

    // PV (swapped): O^T[d][q]
#pragma unroll
    for (int td = 0; td < 2; ++td)
#pragma unroll
      for (int ks = 0; ks < 4; ++ks) {
        int row = td * 32 + l31;
        s16x8 vf = *(const s16x8*)(Vs + row * 128 + ((ks * 32 + hi * 16) ^ ((row & 7) << 4)));
        oacc[td] = mfma32(vf, pf[ks], oacc[td]);
      }

    asm volatile("s_waitcnt vmcnt(0)" ::: "memory");
    __syncthreads();
  }

  // epilogue: normalize, LDS transpose (per-wave 4KB), coalesced store
  float inv = 1.0f / l;
  char* Ob = smem + wv * 4096;
#pragma unroll
  for (int td = 0; td < 2; ++td)
#pragma unroll
    for (int i = 0; i < 8; ++i) {
      int r = 2 * i;
      int d = td * 32 + (r & 3) + 8 * (r >> 2) + 4 * hi;
      unsigned pk = cvtpk_bf16(oacc[td][r] * inv, oacc[td][r + 1] * inv);
      *(unsigned*)(Ob + l31 * 128 + ((d * 2) ^ ((l31 & 7) << 4))) = pk;
    }
  __syncthreads();
#pragma unroll
  for (int p4 = 0; p4 < 4; ++p4) {
    int lq = p4 * 8 + (lane >> 3);
    int col = (lane & 7) * 16;
    s16x8 v0 = *(const s16x8*)(Ob + lq * 128 + (col ^ ((lq & 7) << 4)));
    int qg = blockIdx.x * 128 + wv * 32 + lq;
    *(s16x8*)((char*)&ob[((size_t)(b * NS + qg)) * NE + h * ND] + col) = v0;
  }
}

// ---------------- launch ----------------
extern "C" void kernel_launch(void* const* d_in, const int* in_sizes, int n_in,
                              void* d_out, int out_size, void* d_ws, size_t ws_size,
                              hipStream_t stream) {
  const float* queries = (const float*)d_in[0];
  const float* keys = (const float*)d_in[1];
  // d_in[2] (values) is unused by the reference
  const int* mask = (const int*)d_in[3];
  const float* Wq = (const float*)d_in[4];
  const float* bq = (const float*)d_in[5];
  const float* Wk = (const float*)d_in[6];
  const float* bk = (const float*)d_in[7];
  const float* Wv = (const float*)d_in[8];
  const float* bv = (const float*)d_in[9];
  const float* Wo = (const float*)d_in[10];
  const float* bo = (const float*)d_in[11];
  float* out = (float*)d_out;

  char* ws = (char*)d_ws;
  const size_t SZ_X = (size_t)NB * NS * NE * 2;  // 8 MiB
  const size_t SZ_W = (size_t)NE * NE * 2;       // 2 MiB
  unsigned short* qbf = (unsigned short*)(ws);
  unsigned short* kbf = (unsigned short*)(ws + SZ_X);
  unsigned short* wqb = (unsigned short*)(ws + 2 * SZ_X);
  unsigned short* wkb = (unsigned short*)(ws + 2 * SZ_X + SZ_W);
  unsigned short* wvb = (unsigned short*)(ws + 2 * SZ_X + 2 * SZ_W);
  unsigned short* wob = (unsigned short*)(ws + 2 * SZ_X + 3 * SZ_W);
  unsigned short* qp  = (unsigned short*)(ws + 2 * SZ_X + 4 * SZ_W);
  unsigned short* kp  = (unsigned short*)(ws + 3 * SZ_X + 4 * SZ_W);
  unsigned short* vtp = (unsigned short*)(ws + 4 * SZ_X + 4 * SZ_W);
  unsigned short* ao  = (unsigned short*)(ws + 5 * SZ_X + 4 * SZ_W);

  int nX4 = NB * NS * NE / 4, nW4 = NE * NE / 4;
  conv_x2<<<dim3(1024, 2), 256, 0, stream>>>(queries, keys, qbf, kbf, nX4);
  conv_w4<<<dim3(256, 4), 256, 0, stream>>>(Wq, Wk, Wv, Wo, wqb, wkb, wvb, wob, nW4);

  dim3 gg(NE / 128, (NB * NS) / 64);  // (8, 64)
  gemm_bt<0, 64><<<gg, 256, 0, stream>>>(qbf, wqb, bq, qp, NB * NS, NE, NE);
  gemm_bt<0, 64><<<gg, 256, 0, stream>>>(kbf, wkb, bk, kp, NB * NS, NE, NE);
  gemm_bt<1, 64><<<gg, 256, 0, stream>>>(kbf, wvb, bv, vtp, NB * NS, NE, NE);

  dim3 ga(NS / 128, NB * NH);  // (16, 32)
  attn_fwd<<<ga, 256, 0, stream>>>(qp, kp, vtp, mask, ao);

  gemm_bt<2, 64><<<gg, 256, 0, stream>>>(ao, wob, bo, out, NB * NS, NE, NE);
}